// Round 11
// baseline (263.405 us; speedup 1.0000x reference)
//
#include <hip/hip_runtime.h>
#include <hip/hip_bf16.h>
#include <math.h>

// GCN 5-layer: dims 16->64->128->256->512->1, N=20000, E=320000.
// Round 10: r9 measured-good base (GEMM GBK=32/LDSS=40, prep0 fusion,
// scan_b folded) + ONE reintroduced r6 change: aggregation unroll-8
// (8 independent 16B gathers in flight per lane). If the container failure
// recurs, unroll-8 is the trigger; if it passes, GBK=64 was.

#define N_NODES 20000
#define N_EDGES 320000

typedef __attribute__((ext_vector_type(8))) short short8;
typedef __attribute__((ext_vector_type(4))) float f32x4;

__device__ inline ushort f2bf(float f) {
    __hip_bfloat16 h = __float2bfloat16(f);   // RNE
    return *(ushort*)&h;
}

__device__ inline float bf2f(short s) {
    union { unsigned int u; float f; } c;
    c.u = ((unsigned int)(unsigned short)s) << 16;
    return c.f;
}

// ---------------- prep0: zero cnt + all weight transposes (independent) -----
// wt segments (N*K): 1024, 8192, 32768, 131072 -> total 173056

__global__ void k_prep0(int* __restrict__ cnt, int n,
                        const float* __restrict__ W0, const float* __restrict__ W1,
                        const float* __restrict__ W2, const float* __restrict__ W3,
                        ushort* __restrict__ T0, ushort* __restrict__ T1,
                        ushort* __restrict__ T2, ushort* __restrict__ T3) {
    int i = blockIdx.x * blockDim.x + threadIdx.x;
    if (i < n) cnt[i] = 0;
    const float* W; ushort* T; int K, N, j;
    if (i < 1024)        { W = W0; T = T0; K = 16;  N = 64;  j = i; }
    else if (i < 9216)   { W = W1; T = T1; K = 64;  N = 128; j = i - 1024; }
    else if (i < 41984)  { W = W2; T = T2; K = 128; N = 256; j = i - 9216; }
    else if (i < 173056) { W = W3; T = T3; K = 256; N = 512; j = i - 41984; }
    else return;
    int nn = j / K, kk = j - nn * K;
    T[(size_t)nn * K + kk] = f2bf(W[(size_t)kk * N + nn]);
}

__global__ void k_count(const int* __restrict__ col, int* __restrict__ cnt, int E) {
    int e = blockIdx.x * blockDim.x + threadIdx.x;
    if (e < E) atomicAdd(&cnt[col[e]], 1);
}

// Phase A: 1024 elems/block, block-local exclusive prefix + block total.
__global__ __launch_bounds__(256) void k_scan_a(const int* __restrict__ cnt,
                                                int* __restrict__ rowptr,
                                                int* __restrict__ bsum, int n) {
    __shared__ int s[256];
    int b = blockIdx.x, tid = threadIdx.x;
    int base = b * 1024 + tid * 4;
    int v0 = 0, v1 = 0, v2 = 0, v3 = 0;
    if (base + 3 < n) {
        int4 c = *(const int4*)(cnt + base);
        v0 = c.x; v1 = c.y; v2 = c.z; v3 = c.w;
    } else {
        if (base < n)     v0 = cnt[base];
        if (base + 1 < n) v1 = cnt[base + 1];
        if (base + 2 < n) v2 = cnt[base + 2];
        if (base + 3 < n) v3 = cnt[base + 3];
    }
    s[tid] = v0 + v1 + v2 + v3;
    __syncthreads();
    for (int off = 1; off < 256; off <<= 1) {
        int x = s[tid];
        int add = (tid >= off) ? s[tid - off] : 0;
        __syncthreads();
        s[tid] = x + add;
        __syncthreads();
    }
    int excl = (tid == 0) ? 0 : s[tid - 1];
    if (base < n)     rowptr[base]     = excl;
    if (base + 1 < n) rowptr[base + 1] = excl + v0;
    if (base + 2 < n) rowptr[base + 2] = excl + v0 + v1;
    if (base + 3 < n) rowptr[base + 3] = excl + v0 + v1 + v2;
    if (tid == 255) bsum[b] = s[255];
}

// Phase C (scan_b folded in): each thread serially prefixes the <=20 block
// sums (broadcast L2 reads), adds its offset, emits cursor/deg/dinv.
__global__ void k_scan_c(const int* __restrict__ cnt, int* __restrict__ rowptr,
                         int* __restrict__ cursor, float* __restrict__ deg,
                         float* __restrict__ dinv, const int* __restrict__ bsum,
                         int n, int nblk) {
    int i = blockIdx.x * blockDim.x + threadIdx.x;
    if (i == 0) {
        int tot = 0;
        for (int j = 0; j < nblk; j++) tot += bsum[j];
        rowptr[n] = tot;
    }
    if (i >= n) return;
    int myblk = i >> 10;
    int off = 0;
    for (int j = 0; j < myblk; j++) off += bsum[j];
    int r = rowptr[i] + off;
    rowptr[i] = r;
    cursor[i] = r;
    int c = cnt[i];
    float d = (float)(c + 1);      // in-degree + self-loop
    deg[i] = d;
    dinv[i] = rsqrtf(d);
}

__global__ void k_fill(const int* __restrict__ row, const int* __restrict__ col,
                       const float* __restrict__ dinv, int* __restrict__ cursor,
                       int* __restrict__ csr_src, float* __restrict__ csr_w, int E) {
    int e = blockIdx.x * blockDim.x + threadIdx.x;
    if (e >= E) return;
    int s = row[e], d = col[e];
    int pos = atomicAdd(&cursor[d], 1);
    csr_src[pos] = s;
    csr_w[pos] = dinv[s] * dinv[d];
}

// ---------------- layer-1 pre-aggregation (fp32 x -> bf16 out), d=16 --------

__global__ void k_agg_pre_f32(const float4* __restrict__ h, ushort4* __restrict__ out,
                              const int* __restrict__ rowptr, const int* __restrict__ csr_src,
                              const float* __restrict__ csr_w, const float* __restrict__ deg,
                              const float* __restrict__ dinv, int n) {
    const int g_shift = 2;                       // d=16 -> 4 float4 lanes per node
    int g = 1 << g_shift;
    int grp = threadIdx.x >> g_shift;
    int lane = threadIdx.x & (g - 1);
    int gpb = blockDim.x >> g_shift;
    int v = blockIdx.x * gpb + grp;
    if (v >= n) return;
    float dv = dinv[v];
    float selfw = dv * dv;
    float inv_cnt = 1.0f / deg[v];
    int start = rowptr[v], end = rowptr[v + 1];
    float4 hv = h[(size_t)v * g + lane];
    float4 acc = make_float4(selfw * hv.x, selfw * hv.y, selfw * hv.z, selfw * hv.w);
    int e = start;
    for (; e + 8 <= end; e += 8) {
        int sidx[8]; float ww[8];
        #pragma unroll
        for (int u = 0; u < 8; u++) { sidx[u] = csr_src[e + u]; ww[u] = csr_w[e + u]; }
        float4 hh[8];
        #pragma unroll
        for (int u = 0; u < 8; u++) hh[u] = h[(size_t)sidx[u] * g + lane];
        #pragma unroll
        for (int u = 0; u < 8; u++) {
            acc.x += ww[u] * hh[u].x; acc.y += ww[u] * hh[u].y;
            acc.z += ww[u] * hh[u].z; acc.w += ww[u] * hh[u].w;
        }
    }
    for (; e < end; e++) {
        int s = csr_src[e];
        float w = csr_w[e];
        float4 hs = h[(size_t)s * g + lane];
        acc.x += w * hs.x; acc.y += w * hs.y; acc.z += w * hs.z; acc.w += w * hs.w;
    }
    ushort4 o;
    o.x = f2bf(acc.x * inv_cnt);
    o.y = f2bf(acc.y * inv_cnt);
    o.z = f2bf(acc.z * inv_cnt);
    o.w = f2bf(acc.w * inv_cnt);
    out[(size_t)v * g + lane] = o;
}

// ---------------- bf16 pre-aggregation (layers 2..4), unroll-8 MLP ----------

__global__ void k_agg_pre_bf16(const short8* __restrict__ h, short8* __restrict__ out,
                               const int* __restrict__ rowptr, const int* __restrict__ csr_src,
                               const float* __restrict__ csr_w, const float* __restrict__ deg,
                               const float* __restrict__ dinv, int n, int g_shift) {
    int g = 1 << g_shift;                        // lanes per node = d/8
    int grp = threadIdx.x >> g_shift;
    int lane = threadIdx.x & (g - 1);
    int gpb = blockDim.x >> g_shift;
    int v = blockIdx.x * gpb + grp;
    if (v >= n) return;
    float dv = dinv[v];
    float selfw = dv * dv;
    float inv_cnt = 1.0f / deg[v];
    int start = rowptr[v], end = rowptr[v + 1];

    float acc[8];
    short8 hv = h[(size_t)v * g + lane];
    #pragma unroll
    for (int i = 0; i < 8; i++) acc[i] = selfw * bf2f(hv[i]);

    int e = start;
    for (; e + 8 <= end; e += 8) {
        int sidx[8]; float ww[8];
        #pragma unroll
        for (int u = 0; u < 8; u++) { sidx[u] = csr_src[e + u]; ww[u] = csr_w[e + u]; }
        short8 hh[8];
        #pragma unroll
        for (int u = 0; u < 8; u++) hh[u] = h[(size_t)sidx[u] * g + lane];
        #pragma unroll
        for (int u = 0; u < 8; u++)
            #pragma unroll
            for (int i = 0; i < 8; i++) acc[i] += ww[u] * bf2f(hh[u][i]);
    }
    for (; e < end; e++) {
        int s0 = csr_src[e];
        float w0 = csr_w[e];
        short8 h0 = h[(size_t)s0 * g + lane];
        #pragma unroll
        for (int i = 0; i < 8; i++) acc[i] += w0 * bf2f(h0[i]);
    }
    short8 o;
    #pragma unroll
    for (int i = 0; i < 8; i++) o[i] = (short)f2bf(acc[i] * inv_cnt);
    out[(size_t)v * g + lane] = o;
}

// ---------------- MFMA GEMM: C_bf16[M,N] = relu(A[M,K] @ Wt[N,K]^T + bias) --
// bf16 in/out, fp32 accumulate. 128x128 tile, 4 waves, 4x4 16x16x32 MFMAs.

#define GBM 128
#define GBN 128
#define GBK 32
#define LDSS 40   // LDS row stride in elements (80B, 16B-aligned)

__global__ __launch_bounds__(256) void gemm_mfma(const ushort* __restrict__ A,
                                                 const ushort* __restrict__ Wt,
                                                 const float* __restrict__ bias,
                                                 ushort* __restrict__ C,
                                                 int M, int K, int N, int do_relu) {
    __shared__ ushort As[GBM * LDSS];
    __shared__ ushort Bs[GBN * LDSS];
    int tid = threadIdx.x;
    int wave = tid >> 6;
    int lane = tid & 63;
    int wr = wave >> 1, wc = wave & 1;
    int q = lane >> 4;          // quad 0..3
    int mr = lane & 15;
    int row0 = blockIdx.y * GBM;
    int col0 = blockIdx.x * GBN;

    f32x4 acc[4][4];
    #pragma unroll
    for (int i = 0; i < 4; i++)
        #pragma unroll
        for (int j = 0; j < 4; j++) acc[i][j] = (f32x4){0.f, 0.f, 0.f, 0.f};

    const short8 zero8 = {0, 0, 0, 0, 0, 0, 0, 0};

    for (int k0 = 0; k0 < K; k0 += GBK) {
        #pragma unroll
        for (int it = 0; it < 2; it++) {
            int t = tid + it * 256;
            int r = t >> 2;               // row in tile (0..127)
            int koff = (t & 3) * 8;       // k offset in tile
            int gk = k0 + koff;
            short8 va = zero8;
            int gr = row0 + r;
            if (gr < M && gk < K)
                va = *(const short8*)(A + (size_t)gr * K + gk);
            *(short8*)(As + r * LDSS + koff) = va;
            short8 vb = zero8;
            int gn = col0 + r;
            if (gn < N && gk < K)
                vb = *(const short8*)(Wt + (size_t)gn * K + gk);
            *(short8*)(Bs + r * LDSS + koff) = vb;
        }
        __syncthreads();
        short8 afr[4], bfr[4];
        #pragma unroll
        for (int i = 0; i < 4; i++)
            afr[i] = *(const short8*)(As + (wr * 64 + i * 16 + mr) * LDSS + q * 8);
        #pragma unroll
        for (int j = 0; j < 4; j++)
            bfr[j] = *(const short8*)(Bs + (wc * 64 + j * 16 + mr) * LDSS + q * 8);
        #pragma unroll
        for (int i = 0; i < 4; i++)
            #pragma unroll
            for (int j = 0; j < 4; j++)
                acc[i][j] = __builtin_amdgcn_mfma_f32_16x16x32_bf16(afr[i], bfr[j],
                                                                    acc[i][j], 0, 0, 0);
        __syncthreads();
    }

    // epilogue: C/D layout col=lane&15, row=q*4+reg; emit bf16
    #pragma unroll
    for (int j = 0; j < 4; j++) {
        int col = col0 + wc * 64 + j * 16 + mr;
        if (col >= N) continue;
        float bj = bias[col];
        #pragma unroll
        for (int i = 0; i < 4; i++) {
            int rbase = row0 + wr * 64 + i * 16 + q * 4;
            #pragma unroll
            for (int r = 0; r < 4; r++) {
                int grow = rbase + r;
                if (grow < M) {
                    float v = acc[i][j][r] + bj;
                    if (do_relu) v = fmaxf(v, 0.0f);
                    C[(size_t)grow * N + col] = f2bf(v);
                }
            }
        }
    }
}

// ---------------- final layer ----------------

__global__ void k_dot512_bf16(const short8* __restrict__ A, const float4* __restrict__ w,
                              float* __restrict__ out, int n) {
    int wv = (blockIdx.x * blockDim.x + threadIdx.x) >> 6;
    int lane = threadIdx.x & 63;
    if (wv >= n) return;
    short8 a = A[(size_t)wv * 64 + lane];
    float4 w0 = w[lane * 2], w1 = w[lane * 2 + 1];
    float acc = bf2f(a[0]) * w0.x + bf2f(a[1]) * w0.y + bf2f(a[2]) * w0.z + bf2f(a[3]) * w0.w
              + bf2f(a[4]) * w1.x + bf2f(a[5]) * w1.y + bf2f(a[6]) * w1.z + bf2f(a[7]) * w1.w;
    #pragma unroll
    for (int off = 32; off > 0; off >>= 1) acc += __shfl_down(acc, off, 64);
    if (lane == 0) out[wv] = acc;
}

__global__ void k_agg_final(const float* __restrict__ h, float* __restrict__ out,
                            const int* __restrict__ rowptr, const int* __restrict__ csr_src,
                            const float* __restrict__ csr_w, const float* __restrict__ dinv,
                            const float* __restrict__ b5, int n) {
    int v = blockIdx.x * blockDim.x + threadIdx.x;
    if (v >= n) return;
    float acc = dinv[v] * dinv[v] * h[v];
    int end = rowptr[v + 1];
    for (int e = rowptr[v]; e < end; e++) acc += csr_w[e] * h[csr_src[e]];
    float r = acc + b5[0];                 // 'add' aggregation (output layer)
    out[v] = 1.0f / (1.0f + expf(-r));     // sigmoid
}

// ---------------- launch ----------------

extern "C" void kernel_launch(void* const* d_in, const int* in_sizes, int n_in,
                              void* d_out, int out_size, void* d_ws, size_t ws_size,
                              hipStream_t stream) {
    const float* x   = (const float*)d_in[0];
    const int*   ei  = (const int*)d_in[1];
    const float* W[5] = {(const float*)d_in[2], (const float*)d_in[4], (const float*)d_in[6],
                         (const float*)d_in[8], (const float*)d_in[10]};
    const float* b[5] = {(const float*)d_in[3], (const float*)d_in[5], (const float*)d_in[7],
                         (const float*)d_in[9], (const float*)d_in[11]};
    const int n = in_sizes[0] / 16;
    const int E = in_sizes[1] / 2;
    const int dims[6] = {16, 64, 128, 256, 512, 1};

    const int* e_row = ei;          // src
    const int* e_col = ei + E;      // dst

    // workspace layout
    float* bufA_f = (float*)d_ws;                     // n*512 floats region
    float* bufB_f = bufA_f + (size_t)n * 512;         // n*512 floats region
    ushort* bufA  = (ushort*)bufA_f;                  // h (GEMM out, bf16)
    ushort* bufB  = (ushort*)bufB_f;                  // agg out (bf16)
    int*   cnt    = (int*)(bufB_f + (size_t)n * 512); // n
    int*   rowptr = cnt + n;                          // n+1 (pad to n+4)
    int*   cursor = rowptr + n + 4;                   // n
    float* deg    = (float*)(cursor + n);             // n
    float* dinv   = deg + n;                          // n
    int*   csr_src= (int*)(dinv + n);                 // E
    float* csr_w  = (float*)(csr_src + E);            // E
    ushort* wt0   = (ushort*)(csr_w + E);             // bf16 transposed weights
    ushort* wt1   = wt0 + 16 * 64;
    ushort* wt2   = wt1 + 64 * 128;
    ushort* wt3   = wt2 + 128 * 256;
    int*   bsum   = (int*)(wt3 + 256 * 512);          // scan block sums (<=64)
    ushort* wts[4] = {wt0, wt1, wt2, wt3};

    const int nblk_scan = (n + 1023) / 1024;          // 20

    // ---- graph prep ----
    k_prep0<<<(173056 + 255) / 256, 256, 0, stream>>>(cnt, n, W[0], W[1], W[2], W[3],
                                                      wt0, wt1, wt2, wt3);
    k_count<<<(E + 255) / 256, 256, 0, stream>>>(e_col, cnt, E);
    k_scan_a<<<nblk_scan, 256, 0, stream>>>(cnt, rowptr, bsum, n);
    k_scan_c<<<(n + 255) / 256, 256, 0, stream>>>(cnt, rowptr, cursor, deg, dinv,
                                                  bsum, n, nblk_scan);
    k_fill<<<(E + 255) / 256, 256, 0, stream>>>(e_row, e_col, dinv, cursor, csr_src, csr_w, E);

    // ---- layer 1: fp32 agg -> bf16, then MFMA GEMM -> bf16 h ----
    {
        int K = 16, M = n, Nd = 64;
        int gpb = 256 >> 2;   // 64 nodes / block
        k_agg_pre_f32<<<(n + gpb - 1) / gpb, 256, 0, stream>>>(
            (const float4*)x, (ushort4*)bufB, rowptr, csr_src, csr_w, deg, dinv, n);
        dim3 ggrid((Nd + GBN - 1) / GBN, (M + GBM - 1) / GBM);
        gemm_mfma<<<ggrid, 256, 0, stream>>>(bufB, wts[0], b[0], bufA, M, K, Nd, 1);
    }

    // ---- layers 2..4: bf16 agg -> MFMA GEMM -> bf16 h ----
    for (int l = 1; l < 4; l++) {
        int K = dims[l], M = n, Nd = dims[l + 1];
        int g_shift = (K == 64) ? 3 : (K == 128) ? 4 : 5;   // lanes/node = K/8
        int gpb = 256 >> g_shift;
        k_agg_pre_bf16<<<(n + gpb - 1) / gpb, 256, 0, stream>>>(
            (const short8*)bufA, (short8*)bufB, rowptr, csr_src, csr_w, deg, dinv, n, g_shift);
        dim3 ggrid((Nd + GBN - 1) / GBN, (M + GBM - 1) / GBM);
        gemm_mfma<<<ggrid, 256, 0, stream>>>(bufB, wts[l], b[l], bufA, M, K, Nd, 1);
    }

    // ---- layer 5: bf16 dot + add-aggregate + sigmoid ----
    k_dot512_bf16<<<(n * 64 + 255) / 256, 256, 0, stream>>>(
        (const short8*)bufA, (const float4*)W[4], bufB_f, n);
    k_agg_final<<<(n + 255) / 256, 256, 0, stream>>>(bufB_f, (float*)d_out, rowptr,
                                                     csr_src, csr_w, dinv, b[4], n);
}

// Round 15
// 254.958 us; speedup vs baseline: 1.0331x; 1.0331x over previous
//
#include <hip/hip_runtime.h>
#include <hip/hip_bf16.h>
#include <math.h>

// GCN 5-layer: dims 16->64->128->256->512->1, N=20000, E=320000.
// Round 14 = round 12 resubmitted, 3rd attempt (broker failures are
// time-clustered and source-independent: fails at rounds 7-9 and 12-14,
// passes at 1-6 and 10-11, across three distinct sources incl. this
// minimal audited one). r9 base (narrow GEMM GBK=32/LDSS=40, agg unroll-4)
// + x->bf16 in k_prep0; layer-1 aggregation uses bf16 gather (g_shift=1).

#define N_NODES 20000
#define N_EDGES 320000

typedef __attribute__((ext_vector_type(8))) short short8;
typedef __attribute__((ext_vector_type(4))) float f32x4;

__device__ inline ushort f2bf(float f) {
    __hip_bfloat16 h = __float2bfloat16(f);   // RNE
    return *(ushort*)&h;
}

__device__ inline float bf2f(short s) {
    union { unsigned int u; float f; } c;
    c.u = ((unsigned int)(unsigned short)s) << 16;
    return c.f;
}

// ---------------- prep0: zero cnt + weight transposes + x->bf16 -------------
// wt segments (N*K): 1024, 8192, 32768, 131072 -> total 173056.
// x: nx = n*16 = 320000 elements (row-major [n][16]) -> xb bf16.

__global__ void k_prep0(int* __restrict__ cnt, int n,
                        const float* __restrict__ X, ushort* __restrict__ XB, int nx,
                        const float* __restrict__ W0, const float* __restrict__ W1,
                        const float* __restrict__ W2, const float* __restrict__ W3,
                        ushort* __restrict__ T0, ushort* __restrict__ T1,
                        ushort* __restrict__ T2, ushort* __restrict__ T3) {
    int i = blockIdx.x * blockDim.x + threadIdx.x;
    if (i < n) cnt[i] = 0;
    if (i < nx) XB[i] = f2bf(X[i]);
    const float* W; ushort* T; int K, N, j;
    if (i < 1024)        { W = W0; T = T0; K = 16;  N = 64;  j = i; }
    else if (i < 9216)   { W = W1; T = T1; K = 64;  N = 128; j = i - 1024; }
    else if (i < 41984)  { W = W2; T = T2; K = 128; N = 256; j = i - 9216; }
    else if (i < 173056) { W = W3; T = T3; K = 256; N = 512; j = i - 41984; }
    else return;
    int nn = j / K, kk = j - nn * K;
    T[(size_t)nn * K + kk] = f2bf(W[(size_t)kk * N + nn]);
}

__global__ void k_count(const int* __restrict__ col, int* __restrict__ cnt, int E) {
    int e = blockIdx.x * blockDim.x + threadIdx.x;
    if (e < E) atomicAdd(&cnt[col[e]], 1);
}

// Phase A: 1024 elems/block, block-local exclusive prefix + block total.
__global__ __launch_bounds__(256) void k_scan_a(const int* __restrict__ cnt,
                                                int* __restrict__ rowptr,
                                                int* __restrict__ bsum, int n) {
    __shared__ int s[256];
    int b = blockIdx.x, tid = threadIdx.x;
    int base = b * 1024 + tid * 4;
    int v0 = 0, v1 = 0, v2 = 0, v3 = 0;
    if (base + 3 < n) {
        int4 c = *(const int4*)(cnt + base);
        v0 = c.x; v1 = c.y; v2 = c.z; v3 = c.w;
    } else {
        if (base < n)     v0 = cnt[base];
        if (base + 1 < n) v1 = cnt[base + 1];
        if (base + 2 < n) v2 = cnt[base + 2];
        if (base + 3 < n) v3 = cnt[base + 3];
    }
    s[tid] = v0 + v1 + v2 + v3;
    __syncthreads();
    for (int off = 1; off < 256; off <<= 1) {
        int x = s[tid];
        int add = (tid >= off) ? s[tid - off] : 0;
        __syncthreads();
        s[tid] = x + add;
        __syncthreads();
    }
    int excl = (tid == 0) ? 0 : s[tid - 1];
    if (base < n)     rowptr[base]     = excl;
    if (base + 1 < n) rowptr[base + 1] = excl + v0;
    if (base + 2 < n) rowptr[base + 2] = excl + v0 + v1;
    if (base + 3 < n) rowptr[base + 3] = excl + v0 + v1 + v2;
    if (tid == 255) bsum[b] = s[255];
}

// Phase C (scan_b folded in): each thread serially prefixes the <=20 block
// sums (broadcast L2 reads), adds its offset, emits cursor/deg/dinv.
__global__ void k_scan_c(const int* __restrict__ cnt, int* __restrict__ rowptr,
                         int* __restrict__ cursor, float* __restrict__ deg,
                         float* __restrict__ dinv, const int* __restrict__ bsum,
                         int n, int nblk) {
    int i = blockIdx.x * blockDim.x + threadIdx.x;
    if (i == 0) {
        int tot = 0;
        for (int j = 0; j < nblk; j++) tot += bsum[j];
        rowptr[n] = tot;
    }
    if (i >= n) return;
    int myblk = i >> 10;
    int off = 0;
    for (int j = 0; j < myblk; j++) off += bsum[j];
    int r = rowptr[i] + off;
    rowptr[i] = r;
    cursor[i] = r;
    int c = cnt[i];
    float d = (float)(c + 1);      // in-degree + self-loop
    deg[i] = d;
    dinv[i] = rsqrtf(d);
}

__global__ void k_fill(const int* __restrict__ row, const int* __restrict__ col,
                       const float* __restrict__ dinv, int* __restrict__ cursor,
                       int* __restrict__ csr_src, float* __restrict__ csr_w, int E) {
    int e = blockIdx.x * blockDim.x + threadIdx.x;
    if (e >= E) return;
    int s = row[e], d = col[e];
    int pos = atomicAdd(&cursor[d], 1);
    csr_src[pos] = s;
    csr_w[pos] = dinv[s] * dinv[d];
}

// ---------------- bf16 pre-aggregation (all layers), unroll-4 MLP -----------
// out[v,:] = bf16( (dinv^2 h[v,:] + sum_e w_e h[src_e,:]) / deg[v] ), h bf16.
// g = d/8 lanes per node (g_shift: d=16->1, 64->3, 128->4, 256->5).

__global__ void k_agg_pre_bf16(const short8* __restrict__ h, short8* __restrict__ out,
                               const int* __restrict__ rowptr, const int* __restrict__ csr_src,
                               const float* __restrict__ csr_w, const float* __restrict__ deg,
                               const float* __restrict__ dinv, int n, int g_shift) {
    int g = 1 << g_shift;                        // lanes per node = d/8
    int grp = threadIdx.x >> g_shift;
    int lane = threadIdx.x & (g - 1);
    int gpb = blockDim.x >> g_shift;
    int v = blockIdx.x * gpb + grp;
    if (v >= n) return;
    float dv = dinv[v];
    float selfw = dv * dv;
    float inv_cnt = 1.0f / deg[v];
    int start = rowptr[v], end = rowptr[v + 1];

    float acc[8];
    short8 hv = h[(size_t)v * g + lane];
    #pragma unroll
    for (int i = 0; i < 8; i++) acc[i] = selfw * bf2f(hv[i]);

    int e = start;
    for (; e + 4 <= end; e += 4) {
        int s0 = csr_src[e], s1 = csr_src[e + 1], s2 = csr_src[e + 2], s3 = csr_src[e + 3];
        short8 h0 = h[(size_t)s0 * g + lane];
        short8 h1 = h[(size_t)s1 * g + lane];
        short8 h2 = h[(size_t)s2 * g + lane];
        short8 h3 = h[(size_t)s3 * g + lane];
        float w0 = csr_w[e], w1 = csr_w[e + 1], w2 = csr_w[e + 2], w3 = csr_w[e + 3];
        #pragma unroll
        for (int i = 0; i < 8; i++)
            acc[i] += w0 * bf2f(h0[i]) + w1 * bf2f(h1[i])
                    + w2 * bf2f(h2[i]) + w3 * bf2f(h3[i]);
    }
    for (; e < end; e++) {
        int s0 = csr_src[e];
        float w0 = csr_w[e];
        short8 h0 = h[(size_t)s0 * g + lane];
        #pragma unroll
        for (int i = 0; i < 8; i++) acc[i] += w0 * bf2f(h0[i]);
    }
    short8 o;
    #pragma unroll
    for (int i = 0; i < 8; i++) o[i] = (short)f2bf(acc[i] * inv_cnt);
    out[(size_t)v * g + lane] = o;
}

// ---------------- MFMA GEMM: C_bf16[M,N] = relu(A[M,K] @ Wt[N,K]^T + bias) --
// bf16 in/out, fp32 accumulate. 128x128 tile, 4 waves, 4x4 16x16x32 MFMAs.

#define GBM 128
#define GBN 128
#define GBK 32
#define LDSS 40   // LDS row stride in elements (80B, 16B-aligned)

__global__ __launch_bounds__(256) void gemm_mfma(const ushort* __restrict__ A,
                                                 const ushort* __restrict__ Wt,
                                                 const float* __restrict__ bias,
                                                 ushort* __restrict__ C,
                                                 int M, int K, int N, int do_relu) {
    __shared__ ushort As[GBM * LDSS];
    __shared__ ushort Bs[GBN * LDSS];
    int tid = threadIdx.x;
    int wave = tid >> 6;
    int lane = tid & 63;
    int wr = wave >> 1, wc = wave & 1;
    int q = lane >> 4;          // quad 0..3
    int mr = lane & 15;
    int row0 = blockIdx.y * GBM;
    int col0 = blockIdx.x * GBN;

    f32x4 acc[4][4];
    #pragma unroll
    for (int i = 0; i < 4; i++)
        #pragma unroll
        for (int j = 0; j < 4; j++) acc[i][j] = (f32x4){0.f, 0.f, 0.f, 0.f};

    const short8 zero8 = {0, 0, 0, 0, 0, 0, 0, 0};

    for (int k0 = 0; k0 < K; k0 += GBK) {
        #pragma unroll
        for (int it = 0; it < 2; it++) {
            int t = tid + it * 256;
            int r = t >> 2;               // row in tile (0..127)
            int koff = (t & 3) * 8;       // k offset in tile
            int gk = k0 + koff;
            short8 va = zero8;
            int gr = row0 + r;
            if (gr < M && gk < K)
                va = *(const short8*)(A + (size_t)gr * K + gk);
            *(short8*)(As + r * LDSS + koff) = va;
            short8 vb = zero8;
            int gn = col0 + r;
            if (gn < N && gk < K)
                vb = *(const short8*)(Wt + (size_t)gn * K + gk);
            *(short8*)(Bs + r * LDSS + koff) = vb;
        }
        __syncthreads();
        short8 afr[4], bfr[4];
        #pragma unroll
        for (int i = 0; i < 4; i++)
            afr[i] = *(const short8*)(As + (wr * 64 + i * 16 + mr) * LDSS + q * 8);
        #pragma unroll
        for (int j = 0; j < 4; j++)
            bfr[j] = *(const short8*)(Bs + (wc * 64 + j * 16 + mr) * LDSS + q * 8);
        #pragma unroll
        for (int i = 0; i < 4; i++)
            #pragma unroll
            for (int j = 0; j < 4; j++)
                acc[i][j] = __builtin_amdgcn_mfma_f32_16x16x32_bf16(afr[i], bfr[j],
                                                                    acc[i][j], 0, 0, 0);
        __syncthreads();
    }

    // epilogue: C/D layout col=lane&15, row=q*4+reg; emit bf16
    #pragma unroll
    for (int j = 0; j < 4; j++) {
        int col = col0 + wc * 64 + j * 16 + mr;
        if (col >= N) continue;
        float bj = bias[col];
        #pragma unroll
        for (int i = 0; i < 4; i++) {
            int rbase = row0 + wr * 64 + i * 16 + q * 4;
            #pragma unroll
            for (int r = 0; r < 4; r++) {
                int grow = rbase + r;
                if (grow < M) {
                    float v = acc[i][j][r] + bj;
                    if (do_relu) v = fmaxf(v, 0.0f);
                    C[(size_t)grow * N + col] = f2bf(v);
                }
            }
        }
    }
}

// ---------------- final layer ----------------

__global__ void k_dot512_bf16(const short8* __restrict__ A, const float4* __restrict__ w,
                              float* __restrict__ out, int n) {
    int wv = (blockIdx.x * blockDim.x + threadIdx.x) >> 6;
    int lane = threadIdx.x & 63;
    if (wv >= n) return;
    short8 a = A[(size_t)wv * 64 + lane];
    float4 w0 = w[lane * 2], w1 = w[lane * 2 + 1];
    float acc = bf2f(a[0]) * w0.x + bf2f(a[1]) * w0.y + bf2f(a[2]) * w0.z + bf2f(a[3]) * w0.w
              + bf2f(a[4]) * w1.x + bf2f(a[5]) * w1.y + bf2f(a[6]) * w1.z + bf2f(a[7]) * w1.w;
    #pragma unroll
    for (int off = 32; off > 0; off >>= 1) acc += __shfl_down(acc, off, 64);
    if (lane == 0) out[wv] = acc;
}

__global__ void k_agg_final(const float* __restrict__ h, float* __restrict__ out,
                            const int* __restrict__ rowptr, const int* __restrict__ csr_src,
                            const float* __restrict__ csr_w, const float* __restrict__ dinv,
                            const float* __restrict__ b5, int n) {
    int v = blockIdx.x * blockDim.x + threadIdx.x;
    if (v >= n) return;
    float acc = dinv[v] * dinv[v] * h[v];
    int end = rowptr[v + 1];
    for (int e = rowptr[v]; e < end; e++) acc += csr_w[e] * h[csr_src[e]];
    float r = acc + b5[0];                 // 'add' aggregation (output layer)
    out[v] = 1.0f / (1.0f + expf(-r));     // sigmoid
}

// ---------------- launch ----------------

extern "C" void kernel_launch(void* const* d_in, const int* in_sizes, int n_in,
                              void* d_out, int out_size, void* d_ws, size_t ws_size,
                              hipStream_t stream) {
    const float* x   = (const float*)d_in[0];
    const int*   ei  = (const int*)d_in[1];
    const float* W[5] = {(const float*)d_in[2], (const float*)d_in[4], (const float*)d_in[6],
                         (const float*)d_in[8], (const float*)d_in[10]};
    const float* b[5] = {(const float*)d_in[3], (const float*)d_in[5], (const float*)d_in[7],
                         (const float*)d_in[9], (const float*)d_in[11]};
    const int n = in_sizes[0] / 16;
    const int nx = in_sizes[0];                  // 320000
    const int E = in_sizes[1] / 2;
    const int dims[6] = {16, 64, 128, 256, 512, 1};

    const int* e_row = ei;          // src
    const int* e_col = ei + E;      // dst

    // workspace layout (all segment offsets 16B-aligned)
    float* bufA_f = (float*)d_ws;                     // n*512 floats region
    float* bufB_f = bufA_f + (size_t)n * 512;         // n*512 floats region
    ushort* bufA  = (ushort*)bufA_f;                  // h (GEMM out, bf16)
    ushort* bufB  = (ushort*)bufB_f;                  // agg out (bf16)
    int*   cnt    = (int*)(bufB_f + (size_t)n * 512); // n
    int*   rowptr = cnt + n;                          // n+1 (pad to n+4)
    int*   cursor = rowptr + n + 4;                   // n
    float* deg    = (float*)(cursor + n);             // n
    float* dinv   = deg + n;                          // n
    int*   csr_src= (int*)(dinv + n);                 // E
    float* csr_w  = (float*)(csr_src + E);            // E
    ushort* wt0   = (ushort*)(csr_w + E);             // bf16 transposed weights
    ushort* wt1   = wt0 + 16 * 64;
    ushort* wt2   = wt1 + 64 * 128;
    ushort* wt3   = wt2 + 128 * 256;
    int*   bsum   = (int*)(wt3 + 256 * 512);          // scan block sums (<=64)
    ushort* xb    = (ushort*)(bsum + 64);             // bf16 x, n*16
    ushort* wts[4] = {wt0, wt1, wt2, wt3};

    const int nblk_scan = (n + 1023) / 1024;          // 20

    // ---- graph prep (+ x->bf16) ----
    k_prep0<<<(nx + 255) / 256, 256, 0, stream>>>(cnt, n, x, xb, nx,
                                                  W[0], W[1], W[2], W[3],
                                                  wt0, wt1, wt2, wt3);
    k_count<<<(E + 255) / 256, 256, 0, stream>>>(e_col, cnt, E);
    k_scan_a<<<nblk_scan, 256, 0, stream>>>(cnt, rowptr, bsum, n);
    k_scan_c<<<(n + 255) / 256, 256, 0, stream>>>(cnt, rowptr, cursor, deg, dinv,
                                                  bsum, n, nblk_scan);
    k_fill<<<(E + 255) / 256, 256, 0, stream>>>(e_row, e_col, dinv, cursor, csr_src, csr_w, E);

    // ---- layers 1..4: bf16 agg -> MFMA GEMM -> bf16 h ----
    const ushort* in_feat = xb;
    for (int l = 0; l < 4; l++) {
        int K = dims[l], M = n, Nd = dims[l + 1];
        int g_shift = (K == 16) ? 1 : (K == 64) ? 3 : (K == 128) ? 4 : 5;  // K/8 lanes
        int gpb = 256 >> g_shift;
        k_agg_pre_bf16<<<(n + gpb - 1) / gpb, 256, 0, stream>>>(
            (const short8*)in_feat, (short8*)bufB, rowptr, csr_src, csr_w, deg, dinv,
            n, g_shift);
        dim3 ggrid((Nd + GBN - 1) / GBN, (M + GBM - 1) / GBM);
        gemm_mfma<<<ggrid, 256, 0, stream>>>(bufB, wts[l], b[l], bufA, M, K, Nd, 1);
        in_feat = bufA;
    }

    // ---- layer 5: bf16 dot + add-aggregate + sigmoid ----
    k_dot512_bf16<<<(n * 64 + 255) / 256, 256, 0, stream>>>(
        (const short8*)bufA, (const float4*)W[4], bufB_f, n);
    k_agg_final<<<(n + 255) / 256, 256, 0, stream>>>(bufB_f, (float*)d_out, rowptr,
                                                     csr_src, csr_w, dinv, b[4], n);
}

// Round 16
// 254.341 us; speedup vs baseline: 1.0356x; 1.0024x over previous
//
#include <hip/hip_runtime.h>
#include <hip/hip_bf16.h>
#include <hip/hip_fp8.h>
#include <math.h>

// GCN 5-layer: dims 16->64->128->256->512->1, N=20000, E=320000.
// Round 15: r14 measured base + fp8-e4m3 (scale 32) storage for h3 only:
// layer-3 GEMM epilogue emits fp8(32*h3); layer-4 aggregation (the largest
// gather, d=256) reads fp8 (8 B/lane), decodes to fp32, accumulates, and
// writes bf16 with the 1/32 folded into inv_cnt. Halves the biggest gather's
// bytes. Codec is self-consistent (encode+decode same type) — no MFMA
// format dependency.

#define N_NODES 20000
#define N_EDGES 320000

typedef __attribute__((ext_vector_type(8))) short short8;
typedef __attribute__((ext_vector_type(8))) unsigned char uchar8;
typedef __attribute__((ext_vector_type(4))) float f32x4;

#define H3_SCALE 32.0f

__device__ inline ushort f2bf(float f) {
    __hip_bfloat16 h = __float2bfloat16(f);   // RNE
    return *(ushort*)&h;
}

__device__ inline float bf2f(short s) {
    union { unsigned int u; float f; } c;
    c.u = ((unsigned int)(unsigned short)s) << 16;
    return c.f;
}

__device__ inline unsigned char f2f8(float f) {
    __hip_fp8_e4m3 v(f);                      // OCP e4m3fn, saturating
    return (unsigned char)v.__x;
}

__device__ inline float f82f(unsigned char b) {
    __hip_fp8_e4m3 v; v.__x = b;
    return (float)v;
}

// ---------------- prep0: zero cnt + weight transposes + x->bf16 -------------

__global__ void k_prep0(int* __restrict__ cnt, int n,
                        const float* __restrict__ X, ushort* __restrict__ XB, int nx,
                        const float* __restrict__ W0, const float* __restrict__ W1,
                        const float* __restrict__ W2, const float* __restrict__ W3,
                        ushort* __restrict__ T0, ushort* __restrict__ T1,
                        ushort* __restrict__ T2, ushort* __restrict__ T3) {
    int i = blockIdx.x * blockDim.x + threadIdx.x;
    if (i < n) cnt[i] = 0;
    if (i < nx) XB[i] = f2bf(X[i]);
    const float* W; ushort* T; int K, N, j;
    if (i < 1024)        { W = W0; T = T0; K = 16;  N = 64;  j = i; }
    else if (i < 9216)   { W = W1; T = T1; K = 64;  N = 128; j = i - 1024; }
    else if (i < 41984)  { W = W2; T = T2; K = 128; N = 256; j = i - 9216; }
    else if (i < 173056) { W = W3; T = T3; K = 256; N = 512; j = i - 41984; }
    else return;
    int nn = j / K, kk = j - nn * K;
    T[(size_t)nn * K + kk] = f2bf(W[(size_t)kk * N + nn]);
}

__global__ void k_count(const int* __restrict__ col, int* __restrict__ cnt, int E) {
    int e = blockIdx.x * blockDim.x + threadIdx.x;
    if (e < E) atomicAdd(&cnt[col[e]], 1);
}

// Phase A: 1024 elems/block, block-local exclusive prefix + block total.
__global__ __launch_bounds__(256) void k_scan_a(const int* __restrict__ cnt,
                                                int* __restrict__ rowptr,
                                                int* __restrict__ bsum, int n) {
    __shared__ int s[256];
    int b = blockIdx.x, tid = threadIdx.x;
    int base = b * 1024 + tid * 4;
    int v0 = 0, v1 = 0, v2 = 0, v3 = 0;
    if (base + 3 < n) {
        int4 c = *(const int4*)(cnt + base);
        v0 = c.x; v1 = c.y; v2 = c.z; v3 = c.w;
    } else {
        if (base < n)     v0 = cnt[base];
        if (base + 1 < n) v1 = cnt[base + 1];
        if (base + 2 < n) v2 = cnt[base + 2];
        if (base + 3 < n) v3 = cnt[base + 3];
    }
    s[tid] = v0 + v1 + v2 + v3;
    __syncthreads();
    for (int off = 1; off < 256; off <<= 1) {
        int x = s[tid];
        int add = (tid >= off) ? s[tid - off] : 0;
        __syncthreads();
        s[tid] = x + add;
        __syncthreads();
    }
    int excl = (tid == 0) ? 0 : s[tid - 1];
    if (base < n)     rowptr[base]     = excl;
    if (base + 1 < n) rowptr[base + 1] = excl + v0;
    if (base + 2 < n) rowptr[base + 2] = excl + v0 + v1;
    if (base + 3 < n) rowptr[base + 3] = excl + v0 + v1 + v2;
    if (tid == 255) bsum[b] = s[255];
}

// Phase C: serial prefix of <=20 block sums per thread, emit cursor/deg/dinv.
__global__ void k_scan_c(const int* __restrict__ cnt, int* __restrict__ rowptr,
                         int* __restrict__ cursor, float* __restrict__ deg,
                         float* __restrict__ dinv, const int* __restrict__ bsum,
                         int n, int nblk) {
    int i = blockIdx.x * blockDim.x + threadIdx.x;
    if (i == 0) {
        int tot = 0;
        for (int j = 0; j < nblk; j++) tot += bsum[j];
        rowptr[n] = tot;
    }
    if (i >= n) return;
    int myblk = i >> 10;
    int off = 0;
    for (int j = 0; j < myblk; j++) off += bsum[j];
    int r = rowptr[i] + off;
    rowptr[i] = r;
    cursor[i] = r;
    int c = cnt[i];
    float d = (float)(c + 1);      // in-degree + self-loop
    deg[i] = d;
    dinv[i] = rsqrtf(d);
}

__global__ void k_fill(const int* __restrict__ row, const int* __restrict__ col,
                       const float* __restrict__ dinv, int* __restrict__ cursor,
                       int* __restrict__ csr_src, float* __restrict__ csr_w, int E) {
    int e = blockIdx.x * blockDim.x + threadIdx.x;
    if (e >= E) return;
    int s = row[e], d = col[e];
    int pos = atomicAdd(&cursor[d], 1);
    csr_src[pos] = s;
    csr_w[pos] = dinv[s] * dinv[d];
}

// ---------------- bf16 pre-aggregation (layers 1..3), unroll-4 --------------

__global__ void k_agg_pre_bf16(const short8* __restrict__ h, short8* __restrict__ out,
                               const int* __restrict__ rowptr, const int* __restrict__ csr_src,
                               const float* __restrict__ csr_w, const float* __restrict__ deg,
                               const float* __restrict__ dinv, int n, int g_shift) {
    int g = 1 << g_shift;                        // lanes per node = d/8
    int grp = threadIdx.x >> g_shift;
    int lane = threadIdx.x & (g - 1);
    int gpb = blockDim.x >> g_shift;
    int v = blockIdx.x * gpb + grp;
    if (v >= n) return;
    float dv = dinv[v];
    float selfw = dv * dv;
    float inv_cnt = 1.0f / deg[v];
    int start = rowptr[v], end = rowptr[v + 1];

    float acc[8];
    short8 hv = h[(size_t)v * g + lane];
    #pragma unroll
    for (int i = 0; i < 8; i++) acc[i] = selfw * bf2f(hv[i]);

    int e = start;
    for (; e + 4 <= end; e += 4) {
        int s0 = csr_src[e], s1 = csr_src[e + 1], s2 = csr_src[e + 2], s3 = csr_src[e + 3];
        short8 h0 = h[(size_t)s0 * g + lane];
        short8 h1 = h[(size_t)s1 * g + lane];
        short8 h2 = h[(size_t)s2 * g + lane];
        short8 h3 = h[(size_t)s3 * g + lane];
        float w0 = csr_w[e], w1 = csr_w[e + 1], w2 = csr_w[e + 2], w3 = csr_w[e + 3];
        #pragma unroll
        for (int i = 0; i < 8; i++)
            acc[i] += w0 * bf2f(h0[i]) + w1 * bf2f(h1[i])
                    + w2 * bf2f(h2[i]) + w3 * bf2f(h3[i]);
    }
    for (; e < end; e++) {
        int s0 = csr_src[e];
        float w0 = csr_w[e];
        short8 h0 = h[(size_t)s0 * g + lane];
        #pragma unroll
        for (int i = 0; i < 8; i++) acc[i] += w0 * bf2f(h0[i]);
    }
    short8 o;
    #pragma unroll
    for (int i = 0; i < 8; i++) o[i] = (short)f2bf(acc[i] * inv_cnt);
    out[(size_t)v * g + lane] = o;
}

// ---------------- fp8 pre-aggregation (layer 4, d=256) ----------------------
// h stored as fp8(32*h_true); decode fp32, accumulate, write bf16 with the
// 1/32 folded into the final scale. g=32 lanes/node, 8 features/lane (8B).

__global__ void k_agg_pre_fp8(const uchar8* __restrict__ h, short8* __restrict__ out,
                              const int* __restrict__ rowptr, const int* __restrict__ csr_src,
                              const float* __restrict__ csr_w, const float* __restrict__ deg,
                              const float* __restrict__ dinv, int n) {
    const int g_shift = 5;                       // 32 lanes/node
    int g = 1 << g_shift;
    int grp = threadIdx.x >> g_shift;
    int lane = threadIdx.x & (g - 1);
    int gpb = blockDim.x >> g_shift;
    int v = blockIdx.x * gpb + grp;
    if (v >= n) return;
    float dv = dinv[v];
    float selfw = dv * dv;
    float scale = 1.0f / (deg[v] * H3_SCALE);    // mean + un-scale, folded

    int start = rowptr[v], end = rowptr[v + 1];

    float acc[8];
    uchar8 hv = h[(size_t)v * g + lane];
    #pragma unroll
    for (int i = 0; i < 8; i++) acc[i] = selfw * f82f(hv[i]);

    int e = start;
    for (; e + 4 <= end; e += 4) {
        int s0 = csr_src[e], s1 = csr_src[e + 1], s2 = csr_src[e + 2], s3 = csr_src[e + 3];
        uchar8 h0 = h[(size_t)s0 * g + lane];
        uchar8 h1 = h[(size_t)s1 * g + lane];
        uchar8 h2 = h[(size_t)s2 * g + lane];
        uchar8 h3 = h[(size_t)s3 * g + lane];
        float w0 = csr_w[e], w1 = csr_w[e + 1], w2 = csr_w[e + 2], w3 = csr_w[e + 3];
        #pragma unroll
        for (int i = 0; i < 8; i++)
            acc[i] += w0 * f82f(h0[i]) + w1 * f82f(h1[i])
                    + w2 * f82f(h2[i]) + w3 * f82f(h3[i]);
    }
    for (; e < end; e++) {
        int s0 = csr_src[e];
        float w0 = csr_w[e];
        uchar8 h0 = h[(size_t)s0 * g + lane];
        #pragma unroll
        for (int i = 0; i < 8; i++) acc[i] += w0 * f82f(h0[i]);
    }
    short8 o;
    #pragma unroll
    for (int i = 0; i < 8; i++) o[i] = (short)f2bf(acc[i] * scale);
    out[(size_t)v * g + lane] = o;
}

// ---------------- MFMA GEMM: C = relu(A @ Wt^T + bias) ----------------------
// bf16 inputs, fp32 accumulate. out_fp8=0: emit bf16; out_fp8=1: emit
// fp8(32*v) bytes (layer 3 only). 128x128 tile, 4 waves, 4x4 16x16x32 MFMAs.

#define GBM 128
#define GBN 128
#define GBK 32
#define LDSS 40   // LDS row stride in elements (80B, 16B-aligned)

__global__ __launch_bounds__(256) void gemm_mfma(const ushort* __restrict__ A,
                                                 const ushort* __restrict__ Wt,
                                                 const float* __restrict__ bias,
                                                 void* __restrict__ Cout,
                                                 int M, int K, int N, int out_fp8) {
    __shared__ ushort As[GBM * LDSS];
    __shared__ ushort Bs[GBN * LDSS];
    int tid = threadIdx.x;
    int wave = tid >> 6;
    int lane = tid & 63;
    int wr = wave >> 1, wc = wave & 1;
    int q = lane >> 4;          // quad 0..3
    int mr = lane & 15;
    int row0 = blockIdx.y * GBM;
    int col0 = blockIdx.x * GBN;

    f32x4 acc[4][4];
    #pragma unroll
    for (int i = 0; i < 4; i++)
        #pragma unroll
        for (int j = 0; j < 4; j++) acc[i][j] = (f32x4){0.f, 0.f, 0.f, 0.f};

    const short8 zero8 = {0, 0, 0, 0, 0, 0, 0, 0};

    for (int k0 = 0; k0 < K; k0 += GBK) {
        #pragma unroll
        for (int it = 0; it < 2; it++) {
            int t = tid + it * 256;
            int r = t >> 2;               // row in tile (0..127)
            int koff = (t & 3) * 8;       // k offset in tile
            int gk = k0 + koff;
            short8 va = zero8;
            int gr = row0 + r;
            if (gr < M && gk < K)
                va = *(const short8*)(A + (size_t)gr * K + gk);
            *(short8*)(As + r * LDSS + koff) = va;
            short8 vb = zero8;
            int gn = col0 + r;
            if (gn < N && gk < K)
                vb = *(const short8*)(Wt + (size_t)gn * K + gk);
            *(short8*)(Bs + r * LDSS + koff) = vb;
        }
        __syncthreads();
        short8 afr[4], bfr[4];
        #pragma unroll
        for (int i = 0; i < 4; i++)
            afr[i] = *(const short8*)(As + (wr * 64 + i * 16 + mr) * LDSS + q * 8);
        #pragma unroll
        for (int j = 0; j < 4; j++)
            bfr[j] = *(const short8*)(Bs + (wc * 64 + j * 16 + mr) * LDSS + q * 8);
        #pragma unroll
        for (int i = 0; i < 4; i++)
            #pragma unroll
            for (int j = 0; j < 4; j++)
                acc[i][j] = __builtin_amdgcn_mfma_f32_16x16x32_bf16(afr[i], bfr[j],
                                                                    acc[i][j], 0, 0, 0);
        __syncthreads();
    }

    // epilogue: C/D layout col=lane&15, row=q*4+reg (relu always on here for
    // hidden layers; out_fp8 selects bf16 vs scaled-fp8 emission)
    ushort* C16 = (ushort*)Cout;
    unsigned char* C8 = (unsigned char*)Cout;
    #pragma unroll
    for (int j = 0; j < 4; j++) {
        int col = col0 + wc * 64 + j * 16 + mr;
        if (col >= N) continue;
        float bj = bias[col];
        #pragma unroll
        for (int i = 0; i < 4; i++) {
            int rbase = row0 + wr * 64 + i * 16 + q * 4;
            #pragma unroll
            for (int r = 0; r < 4; r++) {
                int grow = rbase + r;
                if (grow < M) {
                    float v = fmaxf(acc[i][j][r] + bj, 0.0f);
                    if (out_fp8)
                        C8[(size_t)grow * N + col] = f2f8(v * H3_SCALE);
                    else
                        C16[(size_t)grow * N + col] = f2bf(v);
                }
            }
        }
    }
}

// ---------------- final layer ----------------

__global__ void k_dot512_bf16(const short8* __restrict__ A, const float4* __restrict__ w,
                              float* __restrict__ out, int n) {
    int wv = (blockIdx.x * blockDim.x + threadIdx.x) >> 6;
    int lane = threadIdx.x & 63;
    if (wv >= n) return;
    short8 a = A[(size_t)wv * 64 + lane];
    float4 w0 = w[lane * 2], w1 = w[lane * 2 + 1];
    float acc = bf2f(a[0]) * w0.x + bf2f(a[1]) * w0.y + bf2f(a[2]) * w0.z + bf2f(a[3]) * w0.w
              + bf2f(a[4]) * w1.x + bf2f(a[5]) * w1.y + bf2f(a[6]) * w1.z + bf2f(a[7]) * w1.w;
    #pragma unroll
    for (int off = 32; off > 0; off >>= 1) acc += __shfl_down(acc, off, 64);
    if (lane == 0) out[wv] = acc;
}

__global__ void k_agg_final(const float* __restrict__ h, float* __restrict__ out,
                            const int* __restrict__ rowptr, const int* __restrict__ csr_src,
                            const float* __restrict__ csr_w, const float* __restrict__ dinv,
                            const float* __restrict__ b5, int n) {
    int v = blockIdx.x * blockDim.x + threadIdx.x;
    if (v >= n) return;
    float acc = dinv[v] * dinv[v] * h[v];
    int end = rowptr[v + 1];
    for (int e = rowptr[v]; e < end; e++) acc += csr_w[e] * h[csr_src[e]];
    float r = acc + b5[0];                 // 'add' aggregation (output layer)
    out[v] = 1.0f / (1.0f + expf(-r));     // sigmoid
}

// ---------------- launch ----------------

extern "C" void kernel_launch(void* const* d_in, const int* in_sizes, int n_in,
                              void* d_out, int out_size, void* d_ws, size_t ws_size,
                              hipStream_t stream) {
    const float* x   = (const float*)d_in[0];
    const int*   ei  = (const int*)d_in[1];
    const float* W[5] = {(const float*)d_in[2], (const float*)d_in[4], (const float*)d_in[6],
                         (const float*)d_in[8], (const float*)d_in[10]};
    const float* b[5] = {(const float*)d_in[3], (const float*)d_in[5], (const float*)d_in[7],
                         (const float*)d_in[9], (const float*)d_in[11]};
    const int n = in_sizes[0] / 16;
    const int nx = in_sizes[0];                  // 320000
    const int E = in_sizes[1] / 2;
    const int dims[6] = {16, 64, 128, 256, 512, 1};

    const int* e_row = ei;          // src
    const int* e_col = ei + E;      // dst

    // workspace layout (all segment offsets 16B-aligned)
    float* bufA_f = (float*)d_ws;                     // n*512 floats region
    float* bufB_f = bufA_f + (size_t)n * 512;         // n*512 floats region
    ushort* bufA  = (ushort*)bufA_f;                  // h (GEMM out)
    ushort* bufB  = (ushort*)bufB_f;                  // agg out (bf16)
    int*   cnt    = (int*)(bufB_f + (size_t)n * 512); // n
    int*   rowptr = cnt + n;                          // n+1 (pad to n+4)
    int*   cursor = rowptr + n + 4;                   // n
    float* deg    = (float*)(cursor + n);             // n
    float* dinv   = deg + n;                          // n
    int*   csr_src= (int*)(dinv + n);                 // E
    float* csr_w  = (float*)(csr_src + E);            // E
    ushort* wt0   = (ushort*)(csr_w + E);             // bf16 transposed weights
    ushort* wt1   = wt0 + 16 * 64;
    ushort* wt2   = wt1 + 64 * 128;
    ushort* wt3   = wt2 + 128 * 256;
    int*   bsum   = (int*)(wt3 + 256 * 512);          // scan block sums (<=64)
    ushort* xb    = (ushort*)(bsum + 64);             // bf16 x, n*16
    ushort* wts[4] = {wt0, wt1, wt2, wt3};

    const int nblk_scan = (n + 1023) / 1024;          // 20

    // ---- graph prep (+ x->bf16) ----
    k_prep0<<<(nx + 255) / 256, 256, 0, stream>>>(cnt, n, x, xb, nx,
                                                  W[0], W[1], W[2], W[3],
                                                  wt0, wt1, wt2, wt3);
    k_count<<<(E + 255) / 256, 256, 0, stream>>>(e_col, cnt, E);
    k_scan_a<<<nblk_scan, 256, 0, stream>>>(cnt, rowptr, bsum, n);
    k_scan_c<<<(n + 255) / 256, 256, 0, stream>>>(cnt, rowptr, cursor, deg, dinv,
                                                  bsum, n, nblk_scan);
    k_fill<<<(E + 255) / 256, 256, 0, stream>>>(e_row, e_col, dinv, cursor, csr_src, csr_w, E);

    // ---- layers 1..3: bf16 agg -> MFMA GEMM ----
    // layer-3 GEMM emits fp8(32*h3) into bufA for the big layer-4 gather.
    const ushort* in_feat = xb;
    for (int l = 0; l < 3; l++) {
        int K = dims[l], M = n, Nd = dims[l + 1];
        int g_shift = (K == 16) ? 1 : (K == 64) ? 3 : 4;   // K/8 lanes
        int gpb = 256 >> g_shift;
        k_agg_pre_bf16<<<(n + gpb - 1) / gpb, 256, 0, stream>>>(
            (const short8*)in_feat, (short8*)bufB, rowptr, csr_src, csr_w, deg, dinv,
            n, g_shift);
        dim3 ggrid((Nd + GBN - 1) / GBN, (M + GBM - 1) / GBM);
        int out_fp8 = (l == 2) ? 1 : 0;
        gemm_mfma<<<ggrid, 256, 0, stream>>>(bufB, wts[l], b[l], (void*)bufA,
                                             M, K, Nd, out_fp8);
        in_feat = bufA;
    }

    // ---- layer 4: fp8 agg (d=256, half bytes) -> MFMA GEMM (N=512, bf16 out)
    {
        int K = 256, M = n, Nd = 512;
        int gpb = 256 >> 5;   // 8 nodes / block
        k_agg_pre_fp8<<<(n + gpb - 1) / gpb, 256, 0, stream>>>(
            (const uchar8*)bufA, (short8*)bufB, rowptr, csr_src, csr_w, deg, dinv, n);
        dim3 ggrid((Nd + GBN - 1) / GBN, (M + GBM - 1) / GBM);
        gemm_mfma<<<ggrid, 256, 0, stream>>>(bufB, wts[3], b[3], (void*)bufA,
                                             M, K, Nd, 0);
    }

    // ---- layer 5: bf16 dot + add-aggregate + sigmoid ----
    k_dot512_bf16<<<(n * 64 + 255) / 256, 256, 0, stream>>>(
        (const short8*)bufA, (const float4*)W[4], bufB_f, n);
    k_agg_final<<<(n + 255) / 256, 256, 0, stream>>>(bufB_f, (float*)d_out, rowptr,
                                                     csr_src, csr_w, dinv, b[4], n);
}